// Round 1
// baseline (496.379 us; speedup 1.0000x reference)
//
#include <hip/hip_runtime.h>

#define N_NODES 50000
#define N_EDGES 800000
#define DIM 64
#define OUTC 64
#define HEADS 4
#define NREL 32
#define NEG_SLOPE 0.2f

// ---------------- init: out[n][c] = bias[c], denom = 0 ----------------
__global__ __launch_bounds__(256) void init_kernel(float* __restrict__ out,
                                                   float* __restrict__ denom,
                                                   const float* __restrict__ bias) {
    int i = blockIdx.x * 256 + threadIdx.x;
    if (i < N_NODES * OUTC) out[i] = bias[i & 63];
    if (i < N_NODES * HEADS) denom[i] = 0.0f;
}

// ---------------- node transform: xh = x@W, a_src, a_dst ----------------
// One wave per node. Lane l -> head h = l>>4, channels c4 = (l&15)*4 .. +3.
__global__ __launch_bounds__(256) void node_xform(
    const float* __restrict__ x, const float* __restrict__ W,
    const float* __restrict__ att_src, const float* __restrict__ att_dst,
    float* __restrict__ xh, float* __restrict__ a_src, float* __restrict__ a_dst)
{
    __shared__ float Wl[DIM * HEADS * OUTC];  // 64*256 floats = 64 KB
    int tid = threadIdx.x;
    const float4* W4 = (const float4*)W;
    float4* Wl4 = (float4*)Wl;
    #pragma unroll
    for (int i = 0; i < 16; ++i) Wl4[tid + i * 256] = W4[tid + i * 256];
    __syncthreads();

    int lane = tid & 63;
    int warp = tid >> 6;
    int h = lane >> 4;
    int i16 = lane & 15;

    float4 asv = *(const float4*)(att_src + h * 64 + i16 * 4);
    float4 adv = *(const float4*)(att_dst + h * 64 + i16 * 4);

    for (int n = blockIdx.x * 4 + warp; n < N_NODES; n += gridDim.x * 4) {
        float xr = x[n * 64 + lane];
        float4 acc = {0.f, 0.f, 0.f, 0.f};
        #pragma unroll
        for (int k = 0; k < 64; ++k) {
            float xv = __shfl(xr, k);
            float4 wv = Wl4[k * 64 + lane];
            acc.x += xv * wv.x; acc.y += xv * wv.y;
            acc.z += xv * wv.z; acc.w += xv * wv.w;
        }
        ((float4*)xh)[n * 64 + lane] = acc;

        float as = acc.x * asv.x + acc.y * asv.y + acc.z * asv.z + acc.w * asv.w;
        float ad = acc.x * adv.x + acc.y * adv.y + acc.z * adv.z + acc.w * adv.w;
        #pragma unroll
        for (int m = 8; m >= 1; m >>= 1) {
            as += __shfl_xor(as, m);
            ad += __shfl_xor(ad, m);
        }
        if (i16 == 0) {
            a_src[n * 4 + h] = as;
            a_dst[n * 4 + h] = ad;
        }
    }
}

// ---------------- relation table: a_edge_r[r][h] ----------------
// One wave per relation r (R=32 blocks of 64 threads).
__global__ __launch_bounds__(64) void rel_kernel(
    const float* __restrict__ rel_emb, const float* __restrict__ W_e,
    const float* __restrict__ att_edge, float* __restrict__ a_edge_r)
{
    int r = blockIdx.x;
    int lane = threadIdx.x;
    int h = lane >> 4;
    int i16 = lane & 15;

    float rr = rel_emb[r * 64 + lane];
    float4 acc = {0.f, 0.f, 0.f, 0.f};
    #pragma unroll
    for (int k = 0; k < 64; ++k) {
        float rv = __shfl(rr, k);
        float4 wv = *(const float4*)(W_e + k * 256 + h * 64 + i16 * 4);
        acc.x += rv * wv.x; acc.y += rv * wv.y;
        acc.z += rv * wv.z; acc.w += rv * wv.w;
    }
    float4 aev = *(const float4*)(att_edge + h * 64 + i16 * 4);
    float ae = acc.x * aev.x + acc.y * aev.y + acc.z * aev.z + acc.w * aev.w;
    #pragma unroll
    for (int m = 8; m >= 1; m >>= 1) ae += __shfl_xor(ae, m);
    if (i16 == 0) a_edge_r[r * 4 + h] = ae;
}

// ---------------- edge pass 1: ex = exp(leaky_relu(alpha)), denom += ex ----------------
__global__ __launch_bounds__(256) void edge_pass1(
    const int* __restrict__ ei, const int* __restrict__ etype,
    const float* __restrict__ a_src, const float* __restrict__ a_dst,
    const float* __restrict__ a_edge_r, float* __restrict__ ex,
    float* __restrict__ denom)
{
    int e = blockIdx.x * 256 + threadIdx.x;
    if (e >= N_EDGES) return;
    int s = ei[e];
    int d = ei[N_EDGES + e];
    int t = etype[e];
    float4 as = ((const float4*)a_src)[s];
    float4 ad = ((const float4*)a_dst)[d];
    float4 ae = ((const float4*)a_edge_r)[t];

    float a0 = as.x + ad.x + ae.x; a0 = (a0 > 0.f) ? a0 : NEG_SLOPE * a0;
    float a1 = as.y + ad.y + ae.y; a1 = (a1 > 0.f) ? a1 : NEG_SLOPE * a1;
    float a2 = as.z + ad.z + ae.z; a2 = (a2 > 0.f) ? a2 : NEG_SLOPE * a2;
    float a3 = as.w + ad.w + ae.w; a3 = (a3 > 0.f) ? a3 : NEG_SLOPE * a3;

    float4 ev;
    ev.x = __expf(a0); ev.y = __expf(a1); ev.z = __expf(a2); ev.w = __expf(a3);
    ((float4*)ex)[e] = ev;

    atomicAdd(&denom[d * 4 + 0], ev.x);
    atomicAdd(&denom[d * 4 + 1], ev.y);
    atomicAdd(&denom[d * 4 + 2], ev.z);
    atomicAdd(&denom[d * 4 + 3], ev.w);
}

// ---------------- edge pass 2: out[d] += 0.25 * sum_h att[e,h] * xh[s,h,:] ----------------
// One wave per edge; lane = output channel c.
__global__ __launch_bounds__(256) void edge_pass2(
    const int* __restrict__ ei, const float* __restrict__ ex,
    const float* __restrict__ denom, const float* __restrict__ xh,
    float* __restrict__ out)
{
    int lane = threadIdx.x & 63;
    int warp = threadIdx.x >> 6;
    for (int e = blockIdx.x * 4 + warp; e < N_EDGES; e += gridDim.x * 4) {
        int s = ei[e];
        int d = ei[N_EDGES + e];
        float4 ev = ((const float4*)ex)[e];
        float4 dn = ((const float4*)denom)[d];
        float w0 = 0.25f * ev.x / dn.x;
        float w1 = 0.25f * ev.y / dn.y;
        float w2 = 0.25f * ev.z / dn.z;
        float w3 = 0.25f * ev.w / dn.w;
        const float* xr = xh + (size_t)s * 256;
        float val = w0 * xr[lane] + w1 * xr[64 + lane] + w2 * xr[128 + lane] + w3 * xr[192 + lane];
        atomicAdd(&out[d * 64 + lane], val);
    }
}

extern "C" void kernel_launch(void* const* d_in, const int* in_sizes, int n_in,
                              void* d_out, int out_size, void* d_ws, size_t ws_size,
                              hipStream_t stream) {
    const float* x        = (const float*)d_in[0];
    const int*   ei       = (const int*)  d_in[1];
    const int*   etype    = (const int*)  d_in[2];
    const float* rel_emb  = (const float*)d_in[3];
    const float* W        = (const float*)d_in[4];
    const float* W_e      = (const float*)d_in[5];
    const float* att_src  = (const float*)d_in[6];
    const float* att_dst  = (const float*)d_in[7];
    const float* att_edge = (const float*)d_in[8];
    const float* bias     = (const float*)d_in[9];
    float* out = (float*)d_out;

    float* ws       = (float*)d_ws;
    float* xh       = ws;                          // N*256 = 12,800,000
    float* a_src    = xh + (size_t)N_NODES * 256;  // N*4
    float* a_dst    = a_src + N_NODES * 4;         // N*4
    float* a_edge_r = a_dst + N_NODES * 4;         // R*4 = 128
    float* denom    = a_edge_r + NREL * 4;         // N*4
    float* ex       = denom + N_NODES * 4;         // E*4

    init_kernel<<<(N_NODES * OUTC + 255) / 256, 256, 0, stream>>>(out, denom, bias);
    node_xform<<<512, 256, 0, stream>>>(x, W, att_src, att_dst, xh, a_src, a_dst);
    rel_kernel<<<NREL, 64, 0, stream>>>(rel_emb, W_e, att_edge, a_edge_r);
    edge_pass1<<<(N_EDGES + 255) / 256, 256, 0, stream>>>(ei, etype, a_src, a_dst, a_edge_r, ex, denom);
    edge_pass2<<<8192, 256, 0, stream>>>(ei, ex, denom, xh, out);
}

// Round 2
// 404.603 us; speedup vs baseline: 1.2268x; 1.2268x over previous
//
#include <hip/hip_runtime.h>
#include <hip/hip_fp16.h>

#define N_NODES 50000
#define N_EDGES 800000
#define DIM 64
#define OUTC 64
#define HEADS 4
#define NREL 32
#define NEG_SLOPE 0.2f

// ---------------- init: out[n][c] = bias[c], denom = 0 ----------------
__global__ __launch_bounds__(256) void init_kernel(float* __restrict__ out,
                                                   float* __restrict__ denom,
                                                   const float* __restrict__ bias) {
    int i = blockIdx.x * 256 + threadIdx.x;
    if (i < N_NODES * OUTC) out[i] = bias[i & 63];
    if (i < N_NODES * HEADS) denom[i] = 0.0f;
}

// ---------------- node transform: xh = x@W (fp16), a_src, a_dst ----------------
// Block = 256 threads = 256 output channels. Thread tid owns channel c=tid,
// holds W[:,c] in 64 VGPRs. Node index n is wave-uniform (blockIdx-derived)
// so x-row loads scalarize to s_load. Wave w == head h (64 channels/head).
__global__ __launch_bounds__(256) void node_xform(
    const float* __restrict__ x, const float* __restrict__ W,
    const float* __restrict__ att_src, const float* __restrict__ att_dst,
    __half* __restrict__ xh, float* __restrict__ a_src, float* __restrict__ a_dst)
{
    int tid = threadIdx.x;
    int w = tid >> 6;        // wave == head
    int lane = tid & 63;

    float Wreg[64];
    #pragma unroll
    for (int k = 0; k < 64; ++k) Wreg[k] = W[k * 256 + tid];

    float asv = att_src[tid];  // [H][OUT] flat: channel c=tid -> head tid>>6
    float adv = att_dst[tid];

    for (int n = blockIdx.x; n < N_NODES; n += gridDim.x) {
        const float* __restrict__ xr = x + (size_t)n * 64;
        float acc = 0.f;
        #pragma unroll
        for (int k = 0; k < 64; ++k) acc = fmaf(xr[k], Wreg[k], acc);

        xh[(size_t)n * 256 + tid] = __float2half(acc);

        float as = acc * asv;
        float ad = acc * adv;
        #pragma unroll
        for (int m = 32; m >= 1; m >>= 1) {
            as += __shfl_xor(as, m);
            ad += __shfl_xor(ad, m);
        }
        if (lane == 0) {
            a_src[n * 4 + w] = as;
            a_dst[n * 4 + w] = ad;
        }
    }
}

// ---------------- relation table: a_edge_r[r][h] ----------------
__global__ __launch_bounds__(64) void rel_kernel(
    const float* __restrict__ rel_emb, const float* __restrict__ W_e,
    const float* __restrict__ att_edge, float* __restrict__ a_edge_r)
{
    int r = blockIdx.x;
    int lane = threadIdx.x;
    int h = lane >> 4;
    int i16 = lane & 15;

    float rr = rel_emb[r * 64 + lane];
    float4 acc = {0.f, 0.f, 0.f, 0.f};
    #pragma unroll
    for (int k = 0; k < 64; ++k) {
        float rv = __shfl(rr, k);
        float4 wv = *(const float4*)(W_e + k * 256 + h * 64 + i16 * 4);
        acc.x += rv * wv.x; acc.y += rv * wv.y;
        acc.z += rv * wv.z; acc.w += rv * wv.w;
    }
    float4 aev = *(const float4*)(att_edge + h * 64 + i16 * 4);
    float ae = acc.x * aev.x + acc.y * aev.y + acc.z * aev.z + acc.w * aev.w;
    #pragma unroll
    for (int m = 8; m >= 1; m >>= 1) ae += __shfl_xor(ae, m);
    if (i16 == 0) a_edge_r[r * 4 + h] = ae;
}

// ---------------- edge pass 1: ex = exp(leaky_relu(alpha)), denom += ex ----------------
__global__ __launch_bounds__(256) void edge_pass1(
    const int* __restrict__ ei, const int* __restrict__ etype,
    const float* __restrict__ a_src, const float* __restrict__ a_dst,
    const float* __restrict__ a_edge_r, float* __restrict__ ex,
    float* __restrict__ denom)
{
    int e = blockIdx.x * 256 + threadIdx.x;
    if (e >= N_EDGES) return;
    int s = ei[e];
    int d = ei[N_EDGES + e];
    int t = etype[e];
    float4 as = ((const float4*)a_src)[s];
    float4 ad = ((const float4*)a_dst)[d];
    float4 ae = ((const float4*)a_edge_r)[t];

    float a0 = as.x + ad.x + ae.x; a0 = (a0 > 0.f) ? a0 : NEG_SLOPE * a0;
    float a1 = as.y + ad.y + ae.y; a1 = (a1 > 0.f) ? a1 : NEG_SLOPE * a1;
    float a2 = as.z + ad.z + ae.z; a2 = (a2 > 0.f) ? a2 : NEG_SLOPE * a2;
    float a3 = as.w + ad.w + ae.w; a3 = (a3 > 0.f) ? a3 : NEG_SLOPE * a3;

    float4 ev;
    ev.x = __expf(a0); ev.y = __expf(a1); ev.z = __expf(a2); ev.w = __expf(a3);
    ((float4*)ex)[e] = ev;

    atomicAdd(&denom[d * 4 + 0], ev.x);
    atomicAdd(&denom[d * 4 + 1], ev.y);
    atomicAdd(&denom[d * 4 + 2], ev.z);
    atomicAdd(&denom[d * 4 + 3], ev.w);
}

// ---------------- edge pass 2: out[d] += 0.25 * sum_h att[e,h] * xh[s,h,:] ----------------
// One wave per edge; lane = output channel c. fp16 xh gather (512B/edge).
__global__ __launch_bounds__(256) void edge_pass2(
    const int* __restrict__ ei, const float* __restrict__ ex,
    const float* __restrict__ denom, const __half* __restrict__ xh,
    float* __restrict__ out)
{
    int lane = threadIdx.x & 63;
    int warp = threadIdx.x >> 6;
    for (int e = blockIdx.x * 4 + warp; e < N_EDGES; e += gridDim.x * 4) {
        int s = ei[e];
        int d = ei[N_EDGES + e];
        float4 ev = ((const float4*)ex)[e];
        float4 dn = ((const float4*)denom)[d];
        float w0 = 0.25f * ev.x / dn.x;
        float w1 = 0.25f * ev.y / dn.y;
        float w2 = 0.25f * ev.z / dn.z;
        float w3 = 0.25f * ev.w / dn.w;
        const __half* __restrict__ xr = xh + (size_t)s * 256;
        float val = w0 * __half2float(xr[lane])
                  + w1 * __half2float(xr[64 + lane])
                  + w2 * __half2float(xr[128 + lane])
                  + w3 * __half2float(xr[192 + lane]);
        atomicAdd(&out[d * 64 + lane], val);
    }
}

extern "C" void kernel_launch(void* const* d_in, const int* in_sizes, int n_in,
                              void* d_out, int out_size, void* d_ws, size_t ws_size,
                              hipStream_t stream) {
    const float* x        = (const float*)d_in[0];
    const int*   ei       = (const int*)  d_in[1];
    const int*   etype    = (const int*)  d_in[2];
    const float* rel_emb  = (const float*)d_in[3];
    const float* W        = (const float*)d_in[4];
    const float* W_e      = (const float*)d_in[5];
    const float* att_src  = (const float*)d_in[6];
    const float* att_dst  = (const float*)d_in[7];
    const float* att_edge = (const float*)d_in[8];
    const float* bias     = (const float*)d_in[9];
    float* out = (float*)d_out;

    // workspace layout
    char* ws = (char*)d_ws;
    __half* xh     = (__half*)ws;                                  // N*256 halfs = 25.6 MB
    float* a_src   = (float*)(ws + (size_t)N_NODES * 256 * 2);     // N*4
    float* a_dst   = a_src + N_NODES * 4;                          // N*4
    float* a_edge_r= a_dst + N_NODES * 4;                          // R*4
    float* denom   = a_edge_r + NREL * 4;                          // N*4
    float* ex      = denom + N_NODES * 4;                          // E*4

    init_kernel<<<(N_NODES * OUTC + 255) / 256, 256, 0, stream>>>(out, denom, bias);
    node_xform<<<2048, 256, 0, stream>>>(x, W, att_src, att_dst, xh, a_src, a_dst);
    rel_kernel<<<NREL, 64, 0, stream>>>(rel_emb, W_e, att_edge, a_edge_r);
    edge_pass1<<<(N_EDGES + 255) / 256, 256, 0, stream>>>(ei, etype, a_src, a_dst, a_edge_r, ex, denom);
    edge_pass2<<<8192, 256, 0, stream>>>(ei, ex, denom, xh, out);
}

// Round 3
// 382.043 us; speedup vs baseline: 1.2993x; 1.0591x over previous
//
#include <hip/hip_runtime.h>
#include <hip/hip_fp16.h>

#define N_NODES 50000
#define N_EDGES 800000
#define NREL 32
#define NEG_SLOPE 0.2f

// ---------------- CSR build ----------------
__global__ __launch_bounds__(256) void hist_kernel(const int* __restrict__ ei,
                                                   int* __restrict__ counts) {
    int e = blockIdx.x * 256 + threadIdx.x;
    if (e < N_EDGES) atomicAdd(&counts[ei[N_EDGES + e]], 1);
}

__global__ __launch_bounds__(1024) void scan_kernel(const int* __restrict__ counts,
                                                    int* __restrict__ offsets,
                                                    int* __restrict__ cursor) {
    __shared__ int part[1024];
    int tid = threadIdx.x;
    const int PER = (N_NODES + 1023) / 1024;  // 49
    int base = tid * PER;
    int sum = 0;
    for (int i = 0; i < PER; ++i) {
        int idx = base + i;
        if (idx < N_NODES) sum += counts[idx];
    }
    part[tid] = sum;
    __syncthreads();
    for (int off = 1; off < 1024; off <<= 1) {
        int v = (tid >= off) ? part[tid - off] : 0;
        __syncthreads();
        part[tid] += v;
        __syncthreads();
    }
    int run = (tid == 0) ? 0 : part[tid - 1];
    for (int i = 0; i < PER; ++i) {
        int idx = base + i;
        if (idx < N_NODES) {
            offsets[idx] = run;
            cursor[idx] = run;
            run += counts[idx];
        }
    }
}

// pack (src, type) into the bucket: src < 2^16, type < 2^5
__global__ __launch_bounds__(256) void scatter_kernel(const int* __restrict__ ei,
                                                      const int* __restrict__ etype,
                                                      int* __restrict__ cursor,
                                                      int* __restrict__ elist) {
    int e = blockIdx.x * 256 + threadIdx.x;
    if (e >= N_EDGES) return;
    int s = ei[e];
    int d = ei[N_EDGES + e];
    int t = etype[e];
    int pos = atomicAdd(&cursor[d], 1);
    elist[pos] = (s << 5) | t;
}

// ---------------- node transform: xh = x@W (fp16, [N][C][H] layout), a_src, a_dst ----------------
// Thread tid: head h = tid&3, channel c = tid>>2, W column = h*64+c.
// Store xh[n*256 + c*4 + h] = xh[n*256 + tid] -> fully coalesced.
__global__ __launch_bounds__(256) void node_xform(
    const float* __restrict__ x, const float* __restrict__ W,
    const float* __restrict__ att_src, const float* __restrict__ att_dst,
    __half* __restrict__ xh, float* __restrict__ a_src, float* __restrict__ a_dst)
{
    int tid = threadIdx.x;
    int lane = tid & 63;
    int warp = tid >> 6;
    int h = tid & 3;
    int c = tid >> 2;
    int col = h * 64 + c;

    float Wreg[64];
    #pragma unroll
    for (int k = 0; k < 64; ++k) Wreg[k] = W[k * 256 + col];
    float asv = att_src[col];
    float adv = att_dst[col];

    __shared__ float2 red[4][4];  // [warp][head]

    for (int n = blockIdx.x; n < N_NODES; n += gridDim.x) {
        const float* __restrict__ xr = x + (size_t)n * 64;
        float acc = 0.f;
        #pragma unroll
        for (int k = 0; k < 64; ++k) acc = fmaf(xr[k], Wreg[k], acc);
        xh[(size_t)n * 256 + tid] = __float2half(acc);

        float as = acc * asv, ad = acc * adv;
        #pragma unroll
        for (int m = 4; m <= 32; m <<= 1) {
            as += __shfl_xor(as, m);
            ad += __shfl_xor(ad, m);
        }
        // lane&3 == h for lanes 0..3
        if (lane < 4) red[warp][lane] = make_float2(as, ad);
        __syncthreads();
        if (tid < 16) {
            float2 v = red[tid >> 2][tid & 3];
            v.x += __shfl_xor(v.x, 4); v.y += __shfl_xor(v.y, 4);
            v.x += __shfl_xor(v.x, 8); v.y += __shfl_xor(v.y, 8);
            if (tid < 4) { a_src[n * 4 + tid] = v.x; a_dst[n * 4 + tid] = v.y; }
        }
        __syncthreads();
    }
}

// ---------------- relation table: a_edge_r[r][h] ----------------
__global__ __launch_bounds__(64) void rel_kernel(
    const float* __restrict__ rel_emb, const float* __restrict__ W_e,
    const float* __restrict__ att_edge, float* __restrict__ a_edge_r)
{
    int r = blockIdx.x;
    int lane = threadIdx.x;
    int h = lane >> 4;
    int i16 = lane & 15;

    float rr = rel_emb[r * 64 + lane];
    float4 acc = {0.f, 0.f, 0.f, 0.f};
    #pragma unroll
    for (int k = 0; k < 64; ++k) {
        float rv = __shfl(rr, k);
        float4 wv = *(const float4*)(W_e + k * 256 + h * 64 + i16 * 4);
        acc.x += rv * wv.x; acc.y += rv * wv.y;
        acc.z += rv * wv.z; acc.w += rv * wv.w;
    }
    float4 aev = *(const float4*)(att_edge + h * 64 + i16 * 4);
    float ae = acc.x * aev.x + acc.y * aev.y + acc.z * aev.z + acc.w * aev.w;
    #pragma unroll
    for (int m = 8; m >= 1; m >>= 1) ae += __shfl_xor(ae, m);
    if (i16 == 0) a_edge_r[r * 4 + h] = ae;
}

// ---------------- fused aggregate: per dst node, loop incoming edges ----------------
// One wave per node; lane = output channel c. All accumulation in registers.
__global__ __launch_bounds__(256) void aggregate(
    const int* __restrict__ offsets, const int* __restrict__ counts,
    const int* __restrict__ elist, const float* __restrict__ a_src,
    const float* __restrict__ a_dst, const float* __restrict__ a_edge_r,
    const __half* __restrict__ xh, const float* __restrict__ bias,
    float* __restrict__ out)
{
    int lane = threadIdx.x & 63;
    int warp = threadIdx.x >> 6;
    float bv = bias[lane];

    for (int d = blockIdx.x * 4 + warp; d < N_NODES; d += gridDim.x * 4) {
        int beg = offsets[d];
        int deg = counts[d];
        float4 advec = ((const float4*)a_dst)[d];

        float n0 = 0.f, n1 = 0.f, n2 = 0.f, n3 = 0.f;
        float den0 = 0.f, den1 = 0.f, den2 = 0.f, den3 = 0.f;

        for (int base = 0; base < deg; base += 64) {
            int m = deg - base; if (m > 64) m = 64;
            int pk_v = (lane < m) ? elist[beg + base + lane] : 0;
            for (int j = 0; j < m; ++j) {
                int pk = __shfl(pk_v, j);
                int s = pk >> 5;
                int t = pk & 31;
                float4 as = ((const float4*)a_src)[s];
                float4 ae = ((const float4*)a_edge_r)[t];
                float a0 = as.x + advec.x + ae.x; a0 = a0 > 0.f ? a0 : NEG_SLOPE * a0;
                float a1 = as.y + advec.y + ae.y; a1 = a1 > 0.f ? a1 : NEG_SLOPE * a1;
                float a2 = as.z + advec.z + ae.z; a2 = a2 > 0.f ? a2 : NEG_SLOPE * a2;
                float a3 = as.w + advec.w + ae.w; a3 = a3 > 0.f ? a3 : NEG_SLOPE * a3;
                float e0 = __expf(a0), e1 = __expf(a1), e2 = __expf(a2), e3 = __expf(a3);
                den0 += e0; den1 += e1; den2 += e2; den3 += e3;

                const __half2* __restrict__ xr =
                    (const __half2*)(xh + (size_t)s * 256 + lane * 4);
                __half2 p0 = xr[0], p1 = xr[1];
                float2 f0 = __half22float2(p0), f1 = __half22float2(p1);
                n0 = fmaf(e0, f0.x, n0);
                n1 = fmaf(e1, f0.y, n1);
                n2 = fmaf(e2, f1.x, n2);
                n3 = fmaf(e3, f1.y, n3);
            }
        }
        float r = 0.f;
        if (deg > 0)
            r = 0.25f * (n0 / den0 + n1 / den1 + n2 / den2 + n3 / den3);
        out[(size_t)d * 64 + lane] = r + bv;
    }
}

extern "C" void kernel_launch(void* const* d_in, const int* in_sizes, int n_in,
                              void* d_out, int out_size, void* d_ws, size_t ws_size,
                              hipStream_t stream) {
    const float* x        = (const float*)d_in[0];
    const int*   ei       = (const int*)  d_in[1];
    const int*   etype    = (const int*)  d_in[2];
    const float* rel_emb  = (const float*)d_in[3];
    const float* W        = (const float*)d_in[4];
    const float* W_e      = (const float*)d_in[5];
    const float* att_src  = (const float*)d_in[6];
    const float* att_dst  = (const float*)d_in[7];
    const float* att_edge = (const float*)d_in[8];
    const float* bias     = (const float*)d_in[9];
    float* out = (float*)d_out;

    // workspace layout
    char* ws = (char*)d_ws;
    __half* xh      = (__half*)ws;                              // N*256 halfs = 25.6 MB
    char* p = ws + (size_t)N_NODES * 256 * 2;
    float* a_src    = (float*)p;              p += N_NODES * 4 * 4;
    float* a_dst    = (float*)p;              p += N_NODES * 4 * 4;
    float* a_edge_r = (float*)p;              p += NREL * 4 * 4;
    int*   counts   = (int*)p;                p += N_NODES * 4;
    int*   offsets  = (int*)p;                p += N_NODES * 4;
    int*   cursor   = (int*)p;                p += N_NODES * 4;
    int*   elist    = (int*)p;                p += (size_t)N_EDGES * 4;

    hipMemsetAsync(counts, 0, N_NODES * sizeof(int), stream);
    hist_kernel<<<(N_EDGES + 255) / 256, 256, 0, stream>>>(ei, counts);
    scan_kernel<<<1, 1024, 0, stream>>>(counts, offsets, cursor);
    scatter_kernel<<<(N_EDGES + 255) / 256, 256, 0, stream>>>(ei, etype, cursor, elist);
    node_xform<<<2048, 256, 0, stream>>>(x, W, att_src, att_dst, xh, a_src, a_dst);
    rel_kernel<<<NREL, 64, 0, stream>>>(rel_emb, W_e, att_edge, a_edge_r);
    aggregate<<<(N_NODES + 3) / 4, 256, 0, stream>>>(offsets, counts, elist, a_src,
                                                     a_dst, a_edge_r, xh, bias, out);
}

// Round 4
// 271.861 us; speedup vs baseline: 1.8259x; 1.4053x over previous
//
#include <hip/hip_runtime.h>
#include <hip/hip_fp16.h>

#define N_NODES 50000
#define N_EDGES 800000
#define NREL 32
#define NEG_SLOPE 0.2f
#define SCAN_NB ((N_NODES + 255) / 256)   // 196

// ---------------- CSR build ----------------
__global__ __launch_bounds__(256) void hist_kernel(const int* __restrict__ ei,
                                                   int* __restrict__ counts) {
    int e = blockIdx.x * 256 + threadIdx.x;
    if (e < N_EDGES) atomicAdd(&counts[ei[N_EDGES + e]], 1);
}

// block-level exclusive scan: offsets[i] = excl prefix within block, blocksums[b] = block total
__global__ __launch_bounds__(256) void scan1_kernel(const int* __restrict__ counts,
                                                    int* __restrict__ offsets,
                                                    int* __restrict__ blocksums) {
    __shared__ int sh[256];
    int tid = threadIdx.x;
    int i = blockIdx.x * 256 + tid;
    int v = (i < N_NODES) ? counts[i] : 0;
    sh[tid] = v;
    __syncthreads();
    #pragma unroll
    for (int off = 1; off < 256; off <<= 1) {
        int t = (tid >= off) ? sh[tid - off] : 0;
        __syncthreads();
        sh[tid] += t;
        __syncthreads();
    }
    if (i < N_NODES) offsets[i] = sh[tid] - v;
    if (tid == 255) blocksums[blockIdx.x] = sh[255];
}

// scan the 196 block sums (single small block)
__global__ __launch_bounds__(256) void scan2_kernel(int* __restrict__ blocksums,
                                                    int* __restrict__ blockoff) {
    __shared__ int sh[256];
    int tid = threadIdx.x;
    int v = (tid < SCAN_NB) ? blocksums[tid] : 0;
    sh[tid] = v;
    __syncthreads();
    #pragma unroll
    for (int off = 1; off < 256; off <<= 1) {
        int t = (tid >= off) ? sh[tid - off] : 0;
        __syncthreads();
        sh[tid] += t;
        __syncthreads();
    }
    if (tid < SCAN_NB) blockoff[tid] = sh[tid] - v;
}

// add back block offsets, init cursor
__global__ __launch_bounds__(256) void scan3_kernel(int* __restrict__ offsets,
                                                    const int* __restrict__ blockoff,
                                                    int* __restrict__ cursor) {
    int i = blockIdx.x * 256 + threadIdx.x;
    if (i < N_NODES) {
        int o = offsets[i] + blockoff[blockIdx.x];
        offsets[i] = o;
        cursor[i] = o;
    }
}

// pack (src, type) into the bucket: src < 2^16, type < 2^5
__global__ __launch_bounds__(256) void scatter_kernel(const int* __restrict__ ei,
                                                      const int* __restrict__ etype,
                                                      int* __restrict__ cursor,
                                                      int* __restrict__ elist) {
    int e = blockIdx.x * 256 + threadIdx.x;
    if (e >= N_EDGES) return;
    int s = ei[e];
    int d = ei[N_EDGES + e];
    int t = etype[e];
    int pos = atomicAdd(&cursor[d], 1);
    elist[pos] = (s << 5) | t;
}

// ---------------- node transform: xh = x@W (fp16, [N][C][H] layout), a_src, a_dst ----------------
// Thread tid: head h = tid&3, channel c = tid>>2, W column = h*64+c.
__global__ __launch_bounds__(256) void node_xform(
    const float* __restrict__ x, const float* __restrict__ W,
    const float* __restrict__ att_src, const float* __restrict__ att_dst,
    __half* __restrict__ xh, float* __restrict__ a_src, float* __restrict__ a_dst)
{
    int tid = threadIdx.x;
    int lane = tid & 63;
    int warp = tid >> 6;
    int h = tid & 3;
    int c = tid >> 2;
    int col = h * 64 + c;

    float Wreg[64];
    #pragma unroll
    for (int k = 0; k < 64; ++k) Wreg[k] = W[k * 256 + col];
    float asv = att_src[col];
    float adv = att_dst[col];

    __shared__ float2 red[4][4];  // [warp][head]

    for (int n = blockIdx.x; n < N_NODES; n += gridDim.x) {
        const float* __restrict__ xr = x + (size_t)n * 64;
        float acc = 0.f;
        #pragma unroll
        for (int k = 0; k < 64; ++k) acc = fmaf(xr[k], Wreg[k], acc);
        xh[(size_t)n * 256 + tid] = __float2half(acc);

        float as = acc * asv, ad = acc * adv;
        #pragma unroll
        for (int m = 4; m <= 32; m <<= 1) {
            as += __shfl_xor(as, m);
            ad += __shfl_xor(ad, m);
        }
        if (lane < 4) red[warp][lane] = make_float2(as, ad);
        __syncthreads();
        if (tid < 16) {
            float2 v = red[tid >> 2][tid & 3];
            v.x += __shfl_xor(v.x, 4); v.y += __shfl_xor(v.y, 4);
            v.x += __shfl_xor(v.x, 8); v.y += __shfl_xor(v.y, 8);
            if (tid < 4) { a_src[n * 4 + tid] = v.x; a_dst[n * 4 + tid] = v.y; }
        }
        __syncthreads();
    }
}

// ---------------- relation table: a_edge_r[r][h] ----------------
__global__ __launch_bounds__(64) void rel_kernel(
    const float* __restrict__ rel_emb, const float* __restrict__ W_e,
    const float* __restrict__ att_edge, float* __restrict__ a_edge_r)
{
    int r = blockIdx.x;
    int lane = threadIdx.x;
    int h = lane >> 4;
    int i16 = lane & 15;

    float rr = rel_emb[r * 64 + lane];
    float4 acc = {0.f, 0.f, 0.f, 0.f};
    #pragma unroll
    for (int k = 0; k < 64; ++k) {
        float rv = __shfl(rr, k);
        float4 wv = *(const float4*)(W_e + k * 256 + h * 64 + i16 * 4);
        acc.x += rv * wv.x; acc.y += rv * wv.y;
        acc.z += rv * wv.z; acc.w += rv * wv.w;
    }
    float4 aev = *(const float4*)(att_edge + h * 64 + i16 * 4);
    float ae = acc.x * aev.x + acc.y * aev.y + acc.z * aev.z + acc.w * aev.w;
    #pragma unroll
    for (int m = 8; m >= 1; m >>= 1) ae += __shfl_xor(ae, m);
    if (i16 == 0) a_edge_r[r * 4 + h] = ae;
}

// ---------------- fused aggregate: per dst node, loop incoming edges ----------------
__global__ __launch_bounds__(256) void aggregate(
    const int* __restrict__ offsets, const int* __restrict__ counts,
    const int* __restrict__ elist, const float* __restrict__ a_src,
    const float* __restrict__ a_dst, const float* __restrict__ a_edge_r,
    const __half* __restrict__ xh, const float* __restrict__ bias,
    float* __restrict__ out)
{
    int lane = threadIdx.x & 63;
    int warp = threadIdx.x >> 6;
    float bv = bias[lane];

    for (int d = blockIdx.x * 4 + warp; d < N_NODES; d += gridDim.x * 4) {
        int beg = offsets[d];
        int deg = counts[d];
        float4 advec = ((const float4*)a_dst)[d];

        float n0 = 0.f, n1 = 0.f, n2 = 0.f, n3 = 0.f;
        float den0 = 0.f, den1 = 0.f, den2 = 0.f, den3 = 0.f;

        for (int base = 0; base < deg; base += 64) {
            int m = deg - base; if (m > 64) m = 64;
            int pk_v = (lane < m) ? elist[beg + base + lane] : 0;
            for (int j = 0; j < m; ++j) {
                int pk = __shfl(pk_v, j);
                int s = pk >> 5;
                int t = pk & 31;
                float4 as = ((const float4*)a_src)[s];
                float4 ae = ((const float4*)a_edge_r)[t];
                float a0 = as.x + advec.x + ae.x; a0 = a0 > 0.f ? a0 : NEG_SLOPE * a0;
                float a1 = as.y + advec.y + ae.y; a1 = a1 > 0.f ? a1 : NEG_SLOPE * a1;
                float a2 = as.z + advec.z + ae.z; a2 = a2 > 0.f ? a2 : NEG_SLOPE * a2;
                float a3 = as.w + advec.w + ae.w; a3 = a3 > 0.f ? a3 : NEG_SLOPE * a3;
                float e0 = __expf(a0), e1 = __expf(a1), e2 = __expf(a2), e3 = __expf(a3);
                den0 += e0; den1 += e1; den2 += e2; den3 += e3;

                const __half2* __restrict__ xr =
                    (const __half2*)(xh + (size_t)s * 256 + lane * 4);
                __half2 p0 = xr[0], p1 = xr[1];
                float2 f0 = __half22float2(p0), f1 = __half22float2(p1);
                n0 = fmaf(e0, f0.x, n0);
                n1 = fmaf(e1, f0.y, n1);
                n2 = fmaf(e2, f1.x, n2);
                n3 = fmaf(e3, f1.y, n3);
            }
        }
        float r = 0.f;
        if (deg > 0)
            r = 0.25f * (n0 / den0 + n1 / den1 + n2 / den2 + n3 / den3);
        out[(size_t)d * 64 + lane] = r + bv;
    }
}

extern "C" void kernel_launch(void* const* d_in, const int* in_sizes, int n_in,
                              void* d_out, int out_size, void* d_ws, size_t ws_size,
                              hipStream_t stream) {
    const float* x        = (const float*)d_in[0];
    const int*   ei       = (const int*)  d_in[1];
    const int*   etype    = (const int*)  d_in[2];
    const float* rel_emb  = (const float*)d_in[3];
    const float* W        = (const float*)d_in[4];
    const float* W_e      = (const float*)d_in[5];
    const float* att_src  = (const float*)d_in[6];
    const float* att_dst  = (const float*)d_in[7];
    const float* att_edge = (const float*)d_in[8];
    const float* bias     = (const float*)d_in[9];
    float* out = (float*)d_out;

    // workspace layout
    char* ws = (char*)d_ws;
    __half* xh      = (__half*)ws;                              // N*256 halfs = 25.6 MB
    char* p = ws + (size_t)N_NODES * 256 * 2;
    float* a_src    = (float*)p;              p += N_NODES * 4 * 4;
    float* a_dst    = (float*)p;              p += N_NODES * 4 * 4;
    float* a_edge_r = (float*)p;              p += NREL * 4 * 4;
    int*   counts   = (int*)p;                p += N_NODES * 4;
    int*   offsets  = (int*)p;                p += N_NODES * 4;
    int*   cursor   = (int*)p;                p += N_NODES * 4;
    int*   blocksums= (int*)p;                p += 256 * 4;
    int*   blockoff = (int*)p;                p += 256 * 4;
    int*   elist    = (int*)p;                p += (size_t)N_EDGES * 4;

    hipMemsetAsync(counts, 0, N_NODES * sizeof(int), stream);
    hist_kernel<<<(N_EDGES + 255) / 256, 256, 0, stream>>>(ei, counts);
    scan1_kernel<<<SCAN_NB, 256, 0, stream>>>(counts, offsets, blocksums);
    scan2_kernel<<<1, 256, 0, stream>>>(blocksums, blockoff);
    scan3_kernel<<<SCAN_NB, 256, 0, stream>>>(offsets, blockoff, cursor);
    scatter_kernel<<<(N_EDGES + 255) / 256, 256, 0, stream>>>(ei, etype, cursor, elist);
    node_xform<<<2048, 256, 0, stream>>>(x, W, att_src, att_dst, xh, a_src, a_dst);
    rel_kernel<<<NREL, 64, 0, stream>>>(rel_emb, W_e, att_edge, a_edge_r);
    aggregate<<<(N_NODES + 3) / 4, 256, 0, stream>>>(offsets, counts, elist, a_src,
                                                     a_dst, a_edge_r, xh, bias, out);
}

// Round 5
// 222.154 us; speedup vs baseline: 2.2344x; 1.2238x over previous
//
#include <hip/hip_runtime.h>
#include <hip/hip_fp16.h>

#define N_NODES 50000
#define N_EDGES 800000
#define NREL 32
#define NEG_SLOPE 0.2f
#define SCAN_NB ((N_NODES + 255) / 256)   // 196

// ---------------- CSR build ----------------
__global__ __launch_bounds__(256) void hist_kernel(const int* __restrict__ ei,
                                                   int* __restrict__ counts) {
    int e = blockIdx.x * 256 + threadIdx.x;
    if (e < N_EDGES) atomicAdd(&counts[ei[N_EDGES + e]], 1);
}

// block-level exclusive scan
__global__ __launch_bounds__(256) void scan1_kernel(const int* __restrict__ counts,
                                                    int* __restrict__ offsets,
                                                    int* __restrict__ blocksums) {
    __shared__ int sh[256];
    int tid = threadIdx.x;
    int i = blockIdx.x * 256 + tid;
    int v = (i < N_NODES) ? counts[i] : 0;
    sh[tid] = v;
    __syncthreads();
    #pragma unroll
    for (int off = 1; off < 256; off <<= 1) {
        int t = (tid >= off) ? sh[tid - off] : 0;
        __syncthreads();
        sh[tid] += t;
        __syncthreads();
    }
    if (i < N_NODES) offsets[i] = sh[tid] - v;
    if (tid == 255) blocksums[blockIdx.x] = sh[255];
}

__global__ __launch_bounds__(256) void scan2_kernel(int* __restrict__ blocksums,
                                                    int* __restrict__ blockoff) {
    __shared__ int sh[256];
    int tid = threadIdx.x;
    int v = (tid < SCAN_NB) ? blocksums[tid] : 0;
    sh[tid] = v;
    __syncthreads();
    #pragma unroll
    for (int off = 1; off < 256; off <<= 1) {
        int t = (tid >= off) ? sh[tid - off] : 0;
        __syncthreads();
        sh[tid] += t;
        __syncthreads();
    }
    if (tid < SCAN_NB) blockoff[tid] = sh[tid] - v;
}

__global__ __launch_bounds__(256) void scan3_kernel(int* __restrict__ offsets,
                                                    const int* __restrict__ blockoff,
                                                    int* __restrict__ cursor) {
    int i = blockIdx.x * 256 + threadIdx.x;
    if (i < N_NODES) {
        int o = offsets[i] + blockoff[blockIdx.x];
        offsets[i] = o;
        cursor[i] = o;
    }
}

// pack (src, type): src < 2^16, type < 2^5
__global__ __launch_bounds__(256) void scatter_kernel(const int* __restrict__ ei,
                                                      const int* __restrict__ etype,
                                                      int* __restrict__ cursor,
                                                      int* __restrict__ elist) {
    int e = blockIdx.x * 256 + threadIdx.x;
    if (e >= N_EDGES) return;
    int s = ei[e];
    int d = ei[N_EDGES + e];
    int t = etype[e];
    int pos = atomicAdd(&cursor[d], 1);
    elist[pos] = (s << 5) | t;
}

// ---------------- node transform: xh = x@W (fp16, [N][C][H] layout), a_src, a_dst ----------------
__global__ __launch_bounds__(256) void node_xform(
    const float* __restrict__ x, const float* __restrict__ W,
    const float* __restrict__ att_src, const float* __restrict__ att_dst,
    __half* __restrict__ xh, float* __restrict__ a_src, float* __restrict__ a_dst)
{
    int tid = threadIdx.x;
    int lane = tid & 63;
    int warp = tid >> 6;
    int h = tid & 3;
    int c = tid >> 2;
    int col = h * 64 + c;

    float Wreg[64];
    #pragma unroll
    for (int k = 0; k < 64; ++k) Wreg[k] = W[k * 256 + col];
    float asv = att_src[col];
    float adv = att_dst[col];

    __shared__ float2 red[4][4];  // [warp][head]

    for (int n = blockIdx.x; n < N_NODES; n += gridDim.x) {
        const float* __restrict__ xr = x + (size_t)n * 64;
        float acc = 0.f;
        #pragma unroll
        for (int k = 0; k < 64; ++k) acc = fmaf(xr[k], Wreg[k], acc);
        xh[(size_t)n * 256 + tid] = __float2half(acc);

        float as = acc * asv, ad = acc * adv;
        #pragma unroll
        for (int m = 4; m <= 32; m <<= 1) {
            as += __shfl_xor(as, m);
            ad += __shfl_xor(ad, m);
        }
        if (lane < 4) red[warp][lane] = make_float2(as, ad);
        __syncthreads();
        if (tid < 16) {
            float2 v = red[tid >> 2][tid & 3];
            v.x += __shfl_xor(v.x, 4); v.y += __shfl_xor(v.y, 4);
            v.x += __shfl_xor(v.x, 8); v.y += __shfl_xor(v.y, 8);
            if (tid < 4) { a_src[n * 4 + tid] = v.x; a_dst[n * 4 + tid] = v.y; }
        }
        __syncthreads();
    }
}

// ---------------- relation table: a_edge_r[r][h] ----------------
__global__ __launch_bounds__(64) void rel_kernel(
    const float* __restrict__ rel_emb, const float* __restrict__ W_e,
    const float* __restrict__ att_edge, float* __restrict__ a_edge_r)
{
    int r = blockIdx.x;
    int lane = threadIdx.x;
    int h = lane >> 4;
    int i16 = lane & 15;

    float rr = rel_emb[r * 64 + lane];
    float4 acc = {0.f, 0.f, 0.f, 0.f};
    #pragma unroll
    for (int k = 0; k < 64; ++k) {
        float rv = __shfl(rr, k);
        float4 wv = *(const float4*)(W_e + k * 256 + h * 64 + i16 * 4);
        acc.x += rv * wv.x; acc.y += rv * wv.y;
        acc.z += rv * wv.z; acc.w += rv * wv.w;
    }
    float4 aev = *(const float4*)(att_edge + h * 64 + i16 * 4);
    float ae = acc.x * aev.x + acc.y * aev.y + acc.z * aev.z + acc.w * aev.w;
    #pragma unroll
    for (int m = 8; m >= 1; m >>= 1) ae += __shfl_xor(ae, m);
    if (i16 == 0) a_edge_r[r * 4 + h] = ae;
}

// ---------------- fused aggregate ----------------
// Phase A: lane computes exp for ITS edge of a 64-edge chunk -> LDS (wave-synchronous).
// Phase B: per-edge broadcast from LDS + 8B gather + 4 FMA.
__global__ __launch_bounds__(256) void aggregate(
    const int* __restrict__ offsets, const int* __restrict__ counts,
    const int* __restrict__ elist, const float* __restrict__ a_src,
    const float* __restrict__ a_dst, const float* __restrict__ a_edge_r,
    const __half* __restrict__ xh, const float* __restrict__ bias,
    float* __restrict__ out)
{
    __shared__ float4 exsh[4][64];
    __shared__ int    ssh[4][64];
    int lane = threadIdx.x & 63;
    int warp = threadIdx.x >> 6;
    float bv = bias[lane];

    for (int d = blockIdx.x * 4 + warp; d < N_NODES; d += gridDim.x * 4) {
        int beg = offsets[d];
        int deg = counts[d];
        float4 advec = ((const float4*)a_dst)[d];

        float n0 = 0.f, n1 = 0.f, n2 = 0.f, n3 = 0.f;
        float d0 = 0.f, d1 = 0.f, d2 = 0.f, d3 = 0.f;

        for (int base = 0; base < deg; base += 64) {
            int m = deg - base; if (m > 64) m = 64;

            float4 ev = make_float4(0.f, 0.f, 0.f, 0.f);
            int s = 0;
            if (lane < m) {
                int pk = elist[beg + base + lane];
                s = pk >> 5;
                int t = pk & 31;
                float4 as = ((const float4*)a_src)[s];
                float4 ae = ((const float4*)a_edge_r)[t];
                float a0 = as.x + advec.x + ae.x; a0 = a0 > 0.f ? a0 : NEG_SLOPE * a0;
                float a1 = as.y + advec.y + ae.y; a1 = a1 > 0.f ? a1 : NEG_SLOPE * a1;
                float a2 = as.z + advec.z + ae.z; a2 = a2 > 0.f ? a2 : NEG_SLOPE * a2;
                float a3 = as.w + advec.w + ae.w; a3 = a3 > 0.f ? a3 : NEG_SLOPE * a3;
                ev.x = __expf(a0); ev.y = __expf(a1);
                ev.z = __expf(a2); ev.w = __expf(a3);
            }
            d0 += ev.x; d1 += ev.y; d2 += ev.z; d3 += ev.w;
            exsh[warp][lane] = ev;   // wave-private rows; wave-synchronous RAW,
            ssh[warp][lane]  = s;    // compiler inserts the lgkmcnt wait

            #pragma unroll 4
            for (int j = 0; j < m; ++j) {
                float4 e = exsh[warp][j];   // broadcast read (no conflict)
                int sj = ssh[warp][j];
                const __half2* __restrict__ xr =
                    (const __half2*)(xh + (size_t)sj * 256 + lane * 4);
                __half2 p0 = xr[0], p1 = xr[1];
                float2 f0 = __half22float2(p0), f1 = __half22float2(p1);
                n0 = fmaf(e.x, f0.x, n0);
                n1 = fmaf(e.y, f0.y, n1);
                n2 = fmaf(e.z, f1.x, n2);
                n3 = fmaf(e.w, f1.y, n3);
            }
        }

        // butterfly-reduce denominators across the wave (once per node)
        #pragma unroll
        for (int msk = 32; msk >= 1; msk >>= 1) {
            d0 += __shfl_xor(d0, msk);
            d1 += __shfl_xor(d1, msk);
            d2 += __shfl_xor(d2, msk);
            d3 += __shfl_xor(d3, msk);
        }

        float r = 0.f;
        if (deg > 0)
            r = 0.25f * (n0 / d0 + n1 / d1 + n2 / d2 + n3 / d3);
        out[(size_t)d * 64 + lane] = r + bv;
    }
}

extern "C" void kernel_launch(void* const* d_in, const int* in_sizes, int n_in,
                              void* d_out, int out_size, void* d_ws, size_t ws_size,
                              hipStream_t stream) {
    const float* x        = (const float*)d_in[0];
    const int*   ei       = (const int*)  d_in[1];
    const int*   etype    = (const int*)  d_in[2];
    const float* rel_emb  = (const float*)d_in[3];
    const float* W        = (const float*)d_in[4];
    const float* W_e      = (const float*)d_in[5];
    const float* att_src  = (const float*)d_in[6];
    const float* att_dst  = (const float*)d_in[7];
    const float* att_edge = (const float*)d_in[8];
    const float* bias     = (const float*)d_in[9];
    float* out = (float*)d_out;

    // workspace layout
    char* ws = (char*)d_ws;
    __half* xh      = (__half*)ws;                              // N*256 halfs = 25.6 MB
    char* p = ws + (size_t)N_NODES * 256 * 2;
    float* a_src    = (float*)p;              p += N_NODES * 4 * 4;
    float* a_dst    = (float*)p;              p += N_NODES * 4 * 4;
    float* a_edge_r = (float*)p;              p += NREL * 4 * 4;
    int*   counts   = (int*)p;                p += N_NODES * 4;
    int*   offsets  = (int*)p;                p += N_NODES * 4;
    int*   cursor   = (int*)p;                p += N_NODES * 4;
    int*   blocksums= (int*)p;                p += 256 * 4;
    int*   blockoff = (int*)p;                p += 256 * 4;
    int*   elist    = (int*)p;                p += (size_t)N_EDGES * 4;

    hipMemsetAsync(counts, 0, N_NODES * sizeof(int), stream);
    hist_kernel<<<(N_EDGES + 255) / 256, 256, 0, stream>>>(ei, counts);
    scan1_kernel<<<SCAN_NB, 256, 0, stream>>>(counts, offsets, blocksums);
    scan2_kernel<<<1, 256, 0, stream>>>(blocksums, blockoff);
    scan3_kernel<<<SCAN_NB, 256, 0, stream>>>(offsets, blockoff, cursor);
    scatter_kernel<<<(N_EDGES + 255) / 256, 256, 0, stream>>>(ei, etype, cursor, elist);
    node_xform<<<2048, 256, 0, stream>>>(x, W, att_src, att_dst, xh, a_src, a_dst);
    rel_kernel<<<NREL, 64, 0, stream>>>(rel_emb, W_e, att_edge, a_edge_r);
    aggregate<<<(N_NODES + 3) / 4, 256, 0, stream>>>(offsets, counts, elist, a_src,
                                                     a_dst, a_edge_r, xh, bias, out);
}

// Round 6
// 221.560 us; speedup vs baseline: 2.2404x; 1.0027x over previous
//
#include <hip/hip_runtime.h>
#include <hip/hip_fp16.h>

#define N_NODES 50000
#define N_EDGES 800000
#define NREL 32
#define NEG_SLOPE 0.2f
#define SCAN_NB ((N_NODES + 255) / 256)   // 196

// ---------------- CSR build ----------------
__global__ __launch_bounds__(256) void hist_kernel(const int* __restrict__ ei,
                                                   int* __restrict__ counts) {
    int e = blockIdx.x * 256 + threadIdx.x;
    if (e < N_EDGES) atomicAdd(&counts[ei[N_EDGES + e]], 1);
}

// block-level exclusive scan
__global__ __launch_bounds__(256) void scan1_kernel(const int* __restrict__ counts,
                                                    int* __restrict__ offsets,
                                                    int* __restrict__ blocksums) {
    __shared__ int sh[256];
    int tid = threadIdx.x;
    int i = blockIdx.x * 256 + tid;
    int v = (i < N_NODES) ? counts[i] : 0;
    sh[tid] = v;
    __syncthreads();
    #pragma unroll
    for (int off = 1; off < 256; off <<= 1) {
        int t = (tid >= off) ? sh[tid - off] : 0;
        __syncthreads();
        sh[tid] += t;
        __syncthreads();
    }
    if (i < N_NODES) offsets[i] = sh[tid] - v;
    if (tid == 255) blocksums[blockIdx.x] = sh[255];
}

__global__ __launch_bounds__(256) void scan2_kernel(int* __restrict__ blocksums,
                                                    int* __restrict__ blockoff) {
    __shared__ int sh[256];
    int tid = threadIdx.x;
    int v = (tid < SCAN_NB) ? blocksums[tid] : 0;
    sh[tid] = v;
    __syncthreads();
    #pragma unroll
    for (int off = 1; off < 256; off <<= 1) {
        int t = (tid >= off) ? sh[tid - off] : 0;
        __syncthreads();
        sh[tid] += t;
        __syncthreads();
    }
    if (tid < SCAN_NB) blockoff[tid] = sh[tid] - v;
}

__global__ __launch_bounds__(256) void scan3_kernel(int* __restrict__ offsets,
                                                    const int* __restrict__ blockoff,
                                                    int* __restrict__ cursor) {
    int i = blockIdx.x * 256 + threadIdx.x;
    if (i < N_NODES) {
        int o = offsets[i] + blockoff[blockIdx.x];
        offsets[i] = o;
        cursor[i] = o;
    }
}

// pack (src, type): src < 2^16, type < 2^5
__global__ __launch_bounds__(256) void scatter_kernel(const int* __restrict__ ei,
                                                      const int* __restrict__ etype,
                                                      int* __restrict__ cursor,
                                                      int* __restrict__ elist) {
    int e = blockIdx.x * 256 + threadIdx.x;
    if (e >= N_EDGES) return;
    int s = ei[e];
    int d = ei[N_EDGES + e];
    int t = etype[e];
    int pos = atomicAdd(&cursor[d], 1);
    elist[pos] = (s << 5) | t;
}

// ---------------- node transform: xh = x@W (fp16, [N][C][H] layout), a_src, a_dst ----------------
// Wave = head h (col = h*64+lane): a_src/a_dst reduce is a pure in-wave butterfly,
// no barriers, no LDS. Two nodes per iteration for s_load latency overlap.
// xh store: [n][c*4+h] (stride-4 halfs per wave; L2 write-combines across waves).
__global__ __launch_bounds__(256) void node_xform(
    const float* __restrict__ x, const float* __restrict__ W,
    const float* __restrict__ att_src, const float* __restrict__ att_dst,
    __half* __restrict__ xh, float* __restrict__ a_src, float* __restrict__ a_dst)
{
    int tid = threadIdx.x;
    int lane = tid & 63;
    int h = tid >> 6;          // wave == head
    int col = h * 64 + lane;

    float Wreg[64];
    #pragma unroll
    for (int k = 0; k < 64; ++k) Wreg[k] = W[k * 256 + col];
    float asv = att_src[col];
    float adv = att_dst[col];

    for (int n = blockIdx.x * 2; n < N_NODES; n += gridDim.x * 2) {
        // two nodes (n, n+1); N_NODES even and n even -> n+1 always valid
        const float* __restrict__ xa = x + (size_t)n * 64;
        const float* __restrict__ xb = xa + 64;
        float accA = 0.f, accB = 0.f;
        #pragma unroll
        for (int k = 0; k < 64; ++k) {
            float wk = Wreg[k];
            accA = fmaf(xa[k], wk, accA);
            accB = fmaf(xb[k], wk, accB);
        }
        xh[(size_t)n * 256 + lane * 4 + h]       = __float2half(accA);
        xh[(size_t)(n + 1) * 256 + lane * 4 + h] = __float2half(accB);

        float asA = accA * asv, adA = accA * adv;
        float asB = accB * asv, adB = accB * adv;
        #pragma unroll
        for (int m = 32; m >= 1; m >>= 1) {
            asA += __shfl_xor(asA, m);
            adA += __shfl_xor(adA, m);
            asB += __shfl_xor(asB, m);
            adB += __shfl_xor(adB, m);
        }
        if (lane == 0) {
            a_src[n * 4 + h] = asA;
            a_dst[n * 4 + h] = adA;
            a_src[(n + 1) * 4 + h] = asB;
            a_dst[(n + 1) * 4 + h] = adB;
        }
    }
}

// ---------------- relation table: a_edge_r[r][h] ----------------
__global__ __launch_bounds__(64) void rel_kernel(
    const float* __restrict__ rel_emb, const float* __restrict__ W_e,
    const float* __restrict__ att_edge, float* __restrict__ a_edge_r)
{
    int r = blockIdx.x;
    int lane = threadIdx.x;
    int h = lane >> 4;
    int i16 = lane & 15;

    float rr = rel_emb[r * 64 + lane];
    float4 acc = {0.f, 0.f, 0.f, 0.f};
    #pragma unroll
    for (int k = 0; k < 64; ++k) {
        float rv = __shfl(rr, k);
        float4 wv = *(const float4*)(W_e + k * 256 + h * 64 + i16 * 4);
        acc.x += rv * wv.x; acc.y += rv * wv.y;
        acc.z += rv * wv.z; acc.w += rv * wv.w;
    }
    float4 aev = *(const float4*)(att_edge + h * 64 + i16 * 4);
    float ae = acc.x * aev.x + acc.y * aev.y + acc.z * aev.z + acc.w * aev.w;
    #pragma unroll
    for (int m = 8; m >= 1; m >>= 1) ae += __shfl_xor(ae, m);
    if (i16 == 0) a_edge_r[r * 4 + h] = ae;
}

// ---------------- fused aggregate ----------------
// Phase A: lane computes exp for ITS edge of a 64-edge chunk -> LDS (wave-synchronous).
// Phase B: per-edge broadcast from LDS + 8B gather + 4 FMA.
__global__ __launch_bounds__(256) void aggregate(
    const int* __restrict__ offsets, const int* __restrict__ counts,
    const int* __restrict__ elist, const float* __restrict__ a_src,
    const float* __restrict__ a_dst, const float* __restrict__ a_edge_r,
    const __half* __restrict__ xh, const float* __restrict__ bias,
    float* __restrict__ out)
{
    __shared__ float4 exsh[4][64];
    __shared__ int    ssh[4][64];
    int lane = threadIdx.x & 63;
    int warp = threadIdx.x >> 6;
    float bv = bias[lane];

    for (int d = blockIdx.x * 4 + warp; d < N_NODES; d += gridDim.x * 4) {
        int beg = offsets[d];
        int deg = counts[d];
        float4 advec = ((const float4*)a_dst)[d];

        float n0 = 0.f, n1 = 0.f, n2 = 0.f, n3 = 0.f;
        float d0 = 0.f, d1 = 0.f, d2 = 0.f, d3 = 0.f;

        for (int base = 0; base < deg; base += 64) {
            int m = deg - base; if (m > 64) m = 64;

            float4 ev = make_float4(0.f, 0.f, 0.f, 0.f);
            int s = 0;
            if (lane < m) {
                int pk = elist[beg + base + lane];
                s = pk >> 5;
                int t = pk & 31;
                float4 as = ((const float4*)a_src)[s];
                float4 ae = ((const float4*)a_edge_r)[t];
                float a0 = as.x + advec.x + ae.x; a0 = a0 > 0.f ? a0 : NEG_SLOPE * a0;
                float a1 = as.y + advec.y + ae.y; a1 = a1 > 0.f ? a1 : NEG_SLOPE * a1;
                float a2 = as.z + advec.z + ae.z; a2 = a2 > 0.f ? a2 : NEG_SLOPE * a2;
                float a3 = as.w + advec.w + ae.w; a3 = a3 > 0.f ? a3 : NEG_SLOPE * a3;
                ev.x = __expf(a0); ev.y = __expf(a1);
                ev.z = __expf(a2); ev.w = __expf(a3);
            }
            d0 += ev.x; d1 += ev.y; d2 += ev.z; d3 += ev.w;
            exsh[warp][lane] = ev;   // wave-private rows; wave-synchronous RAW
            ssh[warp][lane]  = s;

            #pragma unroll 4
            for (int j = 0; j < m; ++j) {
                float4 e = exsh[warp][j];   // broadcast read (no conflict)
                int sj = ssh[warp][j];
                const __half2* __restrict__ xr =
                    (const __half2*)(xh + (size_t)sj * 256 + lane * 4);
                __half2 p0 = xr[0], p1 = xr[1];
                float2 f0 = __half22float2(p0), f1 = __half22float2(p1);
                n0 = fmaf(e.x, f0.x, n0);
                n1 = fmaf(e.y, f0.y, n1);
                n2 = fmaf(e.z, f1.x, n2);
                n3 = fmaf(e.w, f1.y, n3);
            }
        }

        // butterfly-reduce denominators across the wave (once per node)
        #pragma unroll
        for (int msk = 32; msk >= 1; msk >>= 1) {
            d0 += __shfl_xor(d0, msk);
            d1 += __shfl_xor(d1, msk);
            d2 += __shfl_xor(d2, msk);
            d3 += __shfl_xor(d3, msk);
        }

        float r = 0.f;
        if (deg > 0)
            r = 0.25f * (n0 / d0 + n1 / d1 + n2 / d2 + n3 / d3);
        out[(size_t)d * 64 + lane] = r + bv;
    }
}

extern "C" void kernel_launch(void* const* d_in, const int* in_sizes, int n_in,
                              void* d_out, int out_size, void* d_ws, size_t ws_size,
                              hipStream_t stream) {
    const float* x        = (const float*)d_in[0];
    const int*   ei       = (const int*)  d_in[1];
    const int*   etype    = (const int*)  d_in[2];
    const float* rel_emb  = (const float*)d_in[3];
    const float* W        = (const float*)d_in[4];
    const float* W_e      = (const float*)d_in[5];
    const float* att_src  = (const float*)d_in[6];
    const float* att_dst  = (const float*)d_in[7];
    const float* att_edge = (const float*)d_in[8];
    const float* bias     = (const float*)d_in[9];
    float* out = (float*)d_out;

    // workspace layout
    char* ws = (char*)d_ws;
    __half* xh      = (__half*)ws;                              // N*256 halfs = 25.6 MB
    char* p = ws + (size_t)N_NODES * 256 * 2;
    float* a_src    = (float*)p;              p += N_NODES * 4 * 4;
    float* a_dst    = (float*)p;              p += N_NODES * 4 * 4;
    float* a_edge_r = (float*)p;              p += NREL * 4 * 4;
    int*   counts   = (int*)p;                p += N_NODES * 4;
    int*   offsets  = (int*)p;                p += N_NODES * 4;
    int*   cursor   = (int*)p;                p += N_NODES * 4;
    int*   blocksums= (int*)p;                p += 256 * 4;
    int*   blockoff = (int*)p;                p += 256 * 4;
    int*   elist    = (int*)p;                p += (size_t)N_EDGES * 4;

    hipMemsetAsync(counts, 0, N_NODES * sizeof(int), stream);
    hist_kernel<<<(N_EDGES + 255) / 256, 256, 0, stream>>>(ei, counts);
    scan1_kernel<<<SCAN_NB, 256, 0, stream>>>(counts, offsets, blocksums);
    scan2_kernel<<<1, 256, 0, stream>>>(blocksums, blockoff);
    scan3_kernel<<<SCAN_NB, 256, 0, stream>>>(offsets, blockoff, cursor);
    scatter_kernel<<<(N_EDGES + 255) / 256, 256, 0, stream>>>(ei, etype, cursor, elist);
    node_xform<<<2048, 256, 0, stream>>>(x, W, att_src, att_dst, xh, a_src, a_dst);
    rel_kernel<<<NREL, 64, 0, stream>>>(rel_emb, W_e, att_edge, a_edge_r);
    aggregate<<<(N_NODES + 3) / 4, 256, 0, stream>>>(offsets, counts, elist, a_src,
                                                     a_dst, a_edge_r, xh, bias, out);
}